// Round 12
// baseline (381.722 us; speedup 1.0000x reference)
//
#include <hip/hip_runtime.h>
#include <math.h>

// Cyborg stack machine: B=256, S=128, V=512, H=30, N_STACKS=2, R=2, DEPTH=4
// kA (R14): split-f16 MFMA GEMM, 2 col-blocks per row-block (grid 1024).
// kC (R16): row remap — gate rows (0..15) REPLICATED in lanes 0..15 of every
//   wave (16*4 + 128 pushfn + 64 calc = 256 exactly). Gates via in-wave rlane,
//   computed ONE STEP AHEAD pre-barrier (carried prpC/prqC) -> gate LDS reads +
//   exp chain off the critical path. Calc rows publish nnd2 to LDS; next step
//   every lane computes oc[l&31] itself and the fused output expansion uses
//   30 in-wave rlanes (was 8 ds_read_b128 broadcasts). kD stays deleted.

#define SS 128
#define VV 512
#define NROWS 208      // 8 pop + 8 pushop + 128 pushfn + 64 calc
#define ZOFF 1e-6f

// ws layout (float offsets)
#define OFF_I0   0                          // interp0: 32768*208
#define OFF_OC   (32768*208)                // (unused since R15 — kept for layout)
#define OFF_GI   (OFF_OC + 32768*32)        // G[2][32][208]  (stack, basis, row)
#define OFF_M    (OFF_GI + 2*32*208)        // Gram 32*32
#define OFF_A    (OFF_M + 1024)             // A coef 208*3
#define OFF_Bc   (OFF_A + 624)              // B coef 208*3
#define OFF_W0   (OFF_Bc + 624)             // Wh/Wl f16: 2 x [208][512] halves

typedef _Float16 half8 __attribute__((ext_vector_type(8)));
typedef float f32x4 __attribute__((ext_vector_type(4)));
typedef float f32x2 __attribute__((ext_vector_type(2)));

__device__ __forceinline__ float rlane(float v, int lane) {
    return __int_as_float(__builtin_amdgcn_readlane(__float_as_int(v), lane));
}
template <int CTRL>
__device__ __forceinline__ float dpp_add(float x) {
    int y = __builtin_amdgcn_update_dpp(0, __float_as_int(x), CTRL, 0xF, 0xF, true);
    return x + __int_as_float(y);
}
__device__ __forceinline__ float sum16(float x) {
    x = dpp_add<0xB1>(x);    // quad_perm xor1
    x = dpp_add<0x4E>(x);    // quad_perm xor2
    x = dpp_add<0x124>(x);   // row_ror:4
    x = dpp_add<0x128>(x);   // row_ror:8
    return x;
}
__device__ __forceinline__ float swz16(float x) {   // lane ^ 16 within 32-group
    return __int_as_float(__builtin_amdgcn_ds_swizzle(__float_as_int(x), 0x401F));
}
// v_permlane32_swap: lo[i] = x[i&31], hi[i] = x[32+(i&31)]  (pure VALU)
__device__ __forceinline__ void swap32(float x, float& lo, float& hi) {
    float a = x, b = x;
    asm("v_permlane32_swap_b32 %0, %1" : "+v"(a), "+v"(b));
    lo = a; hi = b;
}

__device__ __forceinline__ const float* w_row(int r, const float* pw, const float* pow_,
                                              const float* pfw, const float* cw) {
    if (r < 8)   return pw   + r * 1536;
    if (r < 16)  return pow_ + (r - 8) * 1536;
    if (r < 144) return pfw  + (r - 16) * 1536;
    return cw + (r - 144) * 1536;
}
__device__ __forceinline__ const float* nw_row(int r, const float* pn, const float* pon,
                                               const float* pfn, const float* cn) {
    if (r < 8)   return pn   + r * 3;
    if (r < 16)  return pon  + (r - 8) * 3;
    if (r < 144) return pfn  + (r - 16) * 3;
    return cn + (r - 144) * 3;
}

// ---------------- kernel B: precompute tables ----------------
__global__ void kB(const float* __restrict__ syms, const float* __restrict__ siv,
                   const float* __restrict__ pw, const float* __restrict__ pn,
                   const float* __restrict__ pow_, const float* __restrict__ pon,
                   const float* __restrict__ pfw, const float* __restrict__ pfn,
                   const float* __restrict__ cw, const float* __restrict__ cn,
                   float* __restrict__ ws) {
    int blk = blockIdx.x, tid = threadIdx.x;
    if (blk < 64) {
        int jj = blk >> 5, e = blk & 31;
        __shared__ float bas[512];
        for (int i = tid; i < 512; i += 256)
            bas[i] = (e == 0) ? 1.0f : ((e == 1) ? siv[i] : syms[(e - 2) * 512 + i]);
        __syncthreads();
        if (tid < NROWS) {
            int c = tid;
            const float4* w4 = (const float4*)(w_row(c, pw, pow_, pfw, cw) + (jj + 1) * 512);
            const float4* b4 = (const float4*)bas;
            float s = 0.f;
            for (int q = 0; q < 128; ++q) {
                float4 a = b4[q], b = w4[q];
                s += a.x * b.x + a.y * b.y + a.z * b.z + a.w * b.w;
            }
            ws[OFF_GI + (jj * 32 + e) * 208 + c] = s;
        }
    } else if (blk == 64) {
        __shared__ float basw[32 * 512];
        for (int i = tid; i < 32 * 512; i += 256) {
            int m = i >> 9, v = i & 511;
            basw[i] = (m == 0) ? 1.0f : ((m == 1) ? siv[v] : syms[(m - 2) * 512 + v]);
        }
        __syncthreads();
        for (int p = tid; p < 1024; p += 256) {
            int m = p >> 5, mm = p & 31;
            const float4* a4 = (const float4*)(basw + m * 512);
            const float4* b4 = (const float4*)(basw + mm * 512);
            float s = 0.f;
            for (int q = 0; q < 128; ++q) {
                float4 a = a4[q], b = b4[q];
                s += a.x * b.x + a.y * b.y + a.z * b.z + a.w * b.w;
            }
            ws[OFF_M + p] = s;
        }
    } else if (blk == 65) {
        for (int idx = tid; idx < 624; idx += 256) {
            int r = idx / 3, j = idx % 3;
            const float4* w4 = (const float4*)(w_row(r, pw, pow_, pfw, cw) + j * 512);
            float s = 0.f;
            for (int q = 0; q < 128; ++q) {
                float4 b = w4[q];
                s += b.x * b.x + b.y * b.y + b.z * b.z + b.w * b.w;
            }
            float nrm = fmaxf(sqrtf(s), 1e-8f);
            float nwv = nw_row(r, pn, pon, pfn, cn)[j];
            float sig = 1.f / (1.f + expf(-nwv));
            ws[OFF_A + idx]  = (2.f * sig - 1.f) / nrm;
            ws[OFF_Bc + idx] = 1.f - sig;
        }
    } else {
        int part = blk - 66;
        _Float16* whp = (_Float16*)(ws + OFF_W0);
        _Float16* wlp = whp + 208 * 512;
        for (int i = tid; i < 6656; i += 256) {
            int flat = part * 6656 + i;
            int c = flat >> 9, v = flat & 511;
            float wv = w_row(c, pw, pow_, pfw, cw)[v];
            _Float16 h = (_Float16)wv;
            whp[flat] = h;
            wlp[flat] = (_Float16)(wv - (float)h);
        }
    }
}

// ---------------- kernel A: interp0 via split-f16 MFMA GEMM (R14) ----------------
__global__ __launch_bounds__(256) void kA(const float* __restrict__ x, float* __restrict__ ws) {
    __shared__ half8 AH[2][256];
    __shared__ half8 AL[2][256];
    __shared__ float red[256];
    __shared__ float invx[64];
    const int tid = threadIdx.x;
    const int wid = tid >> 6, l = tid & 63;
    const int bid = blockIdx.x;
    const size_t bt0 = (size_t)(bid >> 1) * 64;

    const int sr = tid >> 2, ss = tid & 3;
    const float* xp = x + (bt0 + sr) * 512 + ss * 8;
    const int wpos = (sr >> 4) * 64 + (sr & 15) + (ss << 4);

    const _Float16* whp = (const _Float16*)(ws + OFF_W0);
    const _Float16* wlp = whp + 208 * 512;

    const int gw = ((bid & 1) << 2) | wid;
    const int nt = (gw < 5) ? 2 : 1;
    const int t0 = (gw < 5) ? (2 * gw) : (5 + gw);

    f32x4 acc[4][2];
#pragma unroll
    for (int m = 0; m < 4; ++m)
#pragma unroll
        for (int tt = 0; tt < 2; ++tt)
            acc[m][tt] = (f32x4){0.f, 0.f, 0.f, 0.f};

    float sumsq = 0.f;
    {
        float v[8];
        *(float4*)v       = *(const float4*)(xp);
        *(float4*)(v + 4) = *(const float4*)(xp + 4);
        half8 hh, hl;
#pragma unroll
        for (int j = 0; j < 8; ++j) {
            sumsq += v[j] * v[j];
            _Float16 h = (_Float16)v[j];
            hh[j] = h;
            hl[j] = (_Float16)(v[j] - (float)h);
        }
        AH[0][wpos] = hh;
        AL[0][wpos] = hl;
    }
    __syncthreads();

    for (int kt = 0; kt < 16; ++kt) {
        const int buf = kt & 1;
        half8 ahm[4], alm[4];
#pragma unroll
        for (int m = 0; m < 4; ++m) {
            ahm[m] = AH[buf][m * 64 + l];
            alm[m] = AL[buf][m * 64 + l];
        }
        float4 xv0, xv1;
        if (kt < 15) {
            xv0 = *(const float4*)(xp + (kt + 1) * 32);
            xv1 = *(const float4*)(xp + (kt + 1) * 32 + 4);
        }
        const int kof = kt * 32 + (l >> 4) * 8;
#pragma unroll
        for (int tt = 0; tt < 2; ++tt) {
            if (tt < nt) {
                const int c = (t0 + tt) * 16 + (l & 15);
                half8 bh = *(const half8*)(whp + c * 512 + kof);
                half8 bl = *(const half8*)(wlp + c * 512 + kof);
#pragma unroll
                for (int m = 0; m < 4; ++m) {
                    acc[m][tt] = __builtin_amdgcn_mfma_f32_16x16x32_f16(ahm[m], bh, acc[m][tt], 0, 0, 0);
                    acc[m][tt] = __builtin_amdgcn_mfma_f32_16x16x32_f16(ahm[m], bl, acc[m][tt], 0, 0, 0);
                    acc[m][tt] = __builtin_amdgcn_mfma_f32_16x16x32_f16(alm[m], bh, acc[m][tt], 0, 0, 0);
                }
            }
        }
        if (kt < 15) {
            float v[8];
            *(float4*)v = xv0; *(float4*)(v + 4) = xv1;
            half8 hh, hl;
#pragma unroll
            for (int j = 0; j < 8; ++j) {
                sumsq += v[j] * v[j];
                _Float16 h = (_Float16)v[j];
                hh[j] = h;
                hl[j] = (_Float16)(v[j] - (float)h);
            }
            AH[buf ^ 1][wpos] = hh;
            AL[buf ^ 1][wpos] = hl;
        }
        __syncthreads();
    }

    red[tid] = sumsq;
    __syncthreads();
    if (tid < 64) {
        float s = red[tid * 4] + red[tid * 4 + 1] + red[tid * 4 + 2] + red[tid * 4 + 3];
        invx[tid] = 1.f / fmaxf(sqrtf(s), 1e-8f);
    }
    __syncthreads();

#pragma unroll
    for (int tt = 0; tt < 2; ++tt) {
        if (tt < nt) {
            const int c = (t0 + tt) * 16 + (l & 15);
            const float A0 = ws[OFF_A + c * 3];
            const float B0 = ws[OFF_Bc + c * 3];
#pragma unroll
            for (int m = 0; m < 4; ++m) {
                const int rbase = m * 16 + (l >> 4) * 4;
#pragma unroll
                for (int j = 0; j < 4; ++j) {
                    const float ix = invx[rbase + j];
                    ws[OFF_I0 + (bt0 + rbase + j) * 208 + c] = A0 * fabsf(acc[m][tt][j]) * ix + B0;
                }
            }
        }
    }
}

// ---------------- kernel C: scan + fused expand, in-wave gates/oc (R16) ----------------
// Row map: l<16 -> gate row l (ALL waves). wave0 l>=16 -> pushfn 16..63;
// wave1 -> 48+l (64..111); wave2 l in [16,32) -> calc 176+l (192..207),
// l>=32 -> pushfn 80+l (112..143); wave3 -> calc 128+l (144..191).
__global__ __attribute__((amdgpu_flat_work_group_size(256, 256), amdgpu_waves_per_eu(1, 1)))
void kC(float* __restrict__ ws, const float* __restrict__ sharp,
        const float* __restrict__ syms, const float* __restrict__ siv,
        float* __restrict__ out) {
    __shared__ float nndL[2][144];     // rows 16..143 used (gates in-wave now)
    __shared__ float nnd2L[2][64];     // calc rows 144..207 -> [r-144]
    const int b = blockIdx.x, tid = threadIdx.x;
    const int wid = tid >> 6, l = tid & 63;
    const int k = l >> 5, m = l & 31;
    int r;
    if (l < 16)           r = l;
    else if (wid == 0)    r = l;
    else if (wid == 1)    r = 48 + l;
    else if (wid == 2)    r = (l < 32) ? (176 + l) : (80 + l);
    else                  r = 128 + l;
    const bool isCalc = (r >= 144);
    const bool wN = (r >= 16) && (r < 144);

    const float* GI = ws + OFF_GI;
    f32x2 GM1[32], GM2[32];
#pragma unroll
    for (int i = 0; i < 32; ++i) {
        float mv = ws[OFF_M + m * 32 + i];
        GM1[i] = (f32x2){GI[i * 208 + r], mv};
        GM2[i] = (f32x2){GI[(32 + i) * 208 + r], mv};
    }
    const float A1 = ws[OFF_A + r * 3 + 1],  A2 = ws[OFF_A + r * 3 + 2];
    const float B1 = ws[OFF_Bc + r * 3 + 1], B2 = ws[OFF_Bc + r * 3 + 2];
    const float sh = sharp[k];

    // expand basis (2 output coords per thread)
    float2 sv2 = *(const float2*)(siv + 2 * tid);
    float2 sy[30];
#pragma unroll
    for (int mm = 0; mm < 30; ++mm)
        sy[mm] = *(const float2*)(syms + mm * 512 + 2 * tid);
    float* outb = out + (size_t)b * SS * 512 + 2 * tid;

    // replicated stack state
    float st[4], p[4];
#pragma unroll
    for (int d = 0; d < 4; ++d) {
        st[d] = (d == 1) ? ((m == 1) ? 1.f : 0.f) : ((m == 0) ? ZOFF : 0.f);
        p[d] = (d == 1) ? 1.f : 0.f;
    }

    const float* i0base = ws + OFF_I0 + (size_t)b * SS * 208;
    const int ioff = isCalc ? 0 : 1;
    float i0use;

    float pk0c = 0.f, pk1c = 0.f;      // peek components (stack0/stack1, coord m)
    float prpC = 0.f, prqC = 0.f;      // carried gates (one step ahead)

    // CA: readlane gather + packed f32x2 FMA; sets pk0c/pk1c from pp
    auto CA = [&](float pp, float iv) -> float {
        float lo, hi;
        swap32(pp, lo, hi);
        pk0c = lo; pk1c = hi;
        f32x2 a1 = (f32x2){0.f, 0.f}, b1 = (f32x2){0.f, 0.f};
        f32x2 a2 = (f32x2){0.f, 0.f}, b2 = (f32x2){0.f, 0.f};
#pragma unroll
        for (int mm = 0; mm < 32; ++mm) {
            float v0 = rlane(pp, mm);
            float v1 = rlane(pp, 32 + mm);
            if (mm & 1) { b1 += GM1[mm] * v0;  b2 += GM2[mm] * v1; }
            else        { a1 += GM1[mm] * v0;  a2 += GM2[mm] * v1; }
        }
        float dd1 = a1.x + b1.x, gq0 = a1.y + b1.y;
        float dd2 = a2.x + b2.x, gq1 = a2.y + b2.y;
        float pm0 = pk0c * gq0;
        float pm1 = pk1c * gq1;
        float q0 = sum16(pm0); q0 += swz16(q0);
        float q1 = sum16(pm1); q1 += swz16(q1);
        float iq0 = __frsqrt_rn(fmaxf(q0, 1e-16f));
        float iq1 = __frsqrt_rn(fmaxf(q1, 1e-16f));
        return iv * (A1 * fabsf(dd1) * iq0 + B1) * (A2 * fabsf(dd2) * iq1 + B2);
    };
    // gates for NEXT step from in-wave gate-row values (lanes 0..15 hold rows 0..15)
    auto gates = [&](float nv) {
        float g[16];
#pragma unroll
        for (int i = 0; i < 16; ++i) g[i] = rlane(nv, i);
        float dp = k ? (fmaxf(g[6],  g[7])  - fmaxf(g[4],  g[5]))
                     : (fmaxf(g[2],  g[3])  - fmaxf(g[0],  g[1]));
        float dq = k ? (fmaxf(g[14], g[15]) - fmaxf(g[12], g[13]))
                     : (fmaxf(g[10], g[11]) - fmaxf(g[8],  g[9]));
        prpC = 1.f / (1.f + __expf(dp * sh));
        prqC = 1.f / (1.f + __expf(dq * sh));
    };

    // ---- prologue: nnd(0), gates(0), peek(0) components ----
    {
        float pk = st[0] * p[0] + st[1] * p[1] + st[2] * p[2] + st[3] * p[3];
        float nv0 = CA(pk, i0base[r]);
        if (wN) nndL[0][r] = nv0;
        gates(nv0);
        i0use = i0base[(size_t)ioff * 208 + r];
    }
    __syncthreads();

    for (int t = 0; t < SS; ++t) {
        int nidx = t + 1 + ioff; if (nidx > SS - 1) nidx = SS - 1;
        float i0nxt = i0base[(size_t)nidx * 208 + r];

        // ---- oc(t-1) + expand(t-1): per-lane oc, in-wave rlane expansion ----
        if (t > 0) {
            const float* n2 = nnd2L[(t - 1) & 1];
            float cx = 0.f, cy = 0.f;
            if (m >= 2) {
                float2 c2 = *(const float2*)(n2 + 2 * m - 4);
                cx = c2.x; cy = c2.y;
            }
            float4 c30 = *(const float4*)(n2 + 60);
            float ocv = cx + cy + (c30.x + c30.y) * pk0c + (c30.z + c30.w) * pk1c;
            float oc0 = rlane(ocv, 0), oc1 = rlane(ocv, 1);
            float o0 = oc0 + oc1 * sv2.x;
            float o1 = oc0 + oc1 * sv2.y;
#pragma unroll
            for (int mm = 0; mm < 30; ++mm) {
                float cv = rlane(ocv, 2 + mm);
                o0 += cv * sy[mm].x;
                o1 += cv * sy[mm].y;
            }
            *(float2*)(outb + (size_t)(t - 1) * 512) = make_float2(o0, o1);
        }

        // ---- pvc (pushfn rows from nndL) + state update (carried gates) ----
        const float* nb = nndL[t & 1];
        float prx = 0.f, pry = 0.f;
        if (m >= 2) {
            float2 pr2 = *(const float2*)(nb + 16 + 64 * k + 2 * m - 4);
            prx = pr2.x; pry = pr2.y;
        }
        float4 t30 = *(const float4*)(nb + 16 + 64 * k + 60);
        float pvc = prx + pry + (t30.x + t30.y) * pk0c + (t30.z + t30.w) * pk1c;

        float prp0 = prpC, prq0 = prqC;
        float prp1 = 1.f - prp0, prq1 = 1.f - prq0;
        float zc = (m == 0) ? ZOFF : 0.f;
        float s1v[4], p1[4];
#pragma unroll
        for (int d = 0; d < 4; ++d) {
            float ps = st[d] * (1.f - p[d]) + zc * p[d];
            s1v[d] = ps * prp0 + st[d] * prp1;
            p1[d] = p[(d + 1) & 3] * prp0 + p[d] * prp1;
        }
#pragma unroll
        for (int d = 0; d < 4; ++d) {
            float pu = p1[(d + 3) & 3];
            float su = s1v[d] * (1.f - pu) + pvc * pu;
            st[d] = su * prq0 + s1v[d] * prq1;
            p[d] = pu * prq0 + p1[d] * prq1;
        }
        float pkp = st[0] * p[0] + st[1] * p[1] + st[2] * p[2] + st[3] * p[3];

        // ---- CA -> nnd(t+1)/nnd2(t); publish; gates(t+1) pre-barrier ----
        float nv = CA(pkp, i0use);
        if (wN) nndL[(t + 1) & 1][r] = nv;
        if (isCalc) nnd2L[t & 1][r - 144] = nv;
        gates(nv);
        __syncthreads();
        i0use = i0nxt;
    }

    // ---- epilogue: oc(SS-1) + expand(SS-1) ----
    {
        const float* n2 = nnd2L[(SS - 1) & 1];
        float cx = 0.f, cy = 0.f;
        if (m >= 2) {
            float2 c2 = *(const float2*)(n2 + 2 * m - 4);
            cx = c2.x; cy = c2.y;
        }
        float4 c30 = *(const float4*)(n2 + 60);
        float ocv = cx + cy + (c30.x + c30.y) * pk0c + (c30.z + c30.w) * pk1c;
        float oc0 = rlane(ocv, 0), oc1 = rlane(ocv, 1);
        float o0 = oc0 + oc1 * sv2.x;
        float o1 = oc0 + oc1 * sv2.y;
#pragma unroll
        for (int mm = 0; mm < 30; ++mm) {
            float cv = rlane(ocv, 2 + mm);
            o0 += cv * sy[mm].x;
            o1 += cv * sy[mm].y;
        }
        *(float2*)(outb + (size_t)(SS - 1) * 512) = make_float2(o0, o1);
    }
}

extern "C" void kernel_launch(void* const* d_in, const int* in_sizes, int n_in,
                              void* d_out, int out_size, void* d_ws, size_t ws_size,
                              hipStream_t stream) {
    const float* x    = (const float*)d_in[0];
    const float* syms = (const float*)d_in[1];
    const float* siv  = (const float*)d_in[2];
    const float* shp  = (const float*)d_in[3];
    const float* pw   = (const float*)d_in[4];
    const float* pn   = (const float*)d_in[5];
    const float* pow_ = (const float*)d_in[6];
    const float* pon  = (const float*)d_in[7];
    const float* pfw  = (const float*)d_in[8];
    const float* pfn  = (const float*)d_in[9];
    const float* cw   = (const float*)d_in[10];
    const float* cn   = (const float*)d_in[11];
    float* ws  = (float*)d_ws;
    float* out = (float*)d_out;

    hipLaunchKernelGGL(kB, dim3(82),   dim3(256), 0, stream,
                       syms, siv, pw, pn, pow_, pon, pfw, pfn, cw, cn, ws);
    hipLaunchKernelGGL(kA, dim3(1024), dim3(256), 0, stream, x, ws);
    hipLaunchKernelGGL(kC, dim3(256),  dim3(256), 0, stream, ws, shp, syms, siv, out);
}

// Round 13
// 371.429 us; speedup vs baseline: 1.0277x; 1.0277x over previous
//
#include <hip/hip_runtime.h>
#include <math.h>

// Cyborg stack machine: B=256, S=128, V=512, H=30, N_STACKS=2, R=2, DEPTH=4
// kA (R14): split-f16 MFMA GEMM, 2 col-blocks per row-block (grid 1024).
// kC (R17): R14 scan (proven 121us) + TAIL-PHASE output expansion.
//   Scan: wave3 writes oc(t) to LDS ocA[128][36] (pad->conflict-free, 1 ds_write).
//   Tail (after loop): each thread expands 4 cols x 64 steps; 8 broadcast b128
//   + 124 FMA per step; basis regs loaded after scan (GM tables freed).
//   Expansion off the serial critical path; kD stays deleted.

#define SS 128
#define VV 512
#define NROWS 208      // 8 pop + 8 pushop + 128 pushfn + 64 calc
#define ZOFF 1e-6f

// ws layout (float offsets)
#define OFF_I0   0                          // interp0: 32768*208
#define OFF_OC   (32768*208)                // (unused since R15 — kept for layout)
#define OFF_GI   (OFF_OC + 32768*32)        // G[2][32][208]  (stack, basis, row)
#define OFF_M    (OFF_GI + 2*32*208)        // Gram 32*32
#define OFF_A    (OFF_M + 1024)             // A coef 208*3
#define OFF_Bc   (OFF_A + 624)              // B coef 208*3
#define OFF_W0   (OFF_Bc + 624)             // Wh/Wl f16: 2 x [208][512] halves

typedef _Float16 half8 __attribute__((ext_vector_type(8)));
typedef float f32x4 __attribute__((ext_vector_type(4)));
typedef float f32x2 __attribute__((ext_vector_type(2)));

__device__ __forceinline__ float rlane(float v, int lane) {
    return __int_as_float(__builtin_amdgcn_readlane(__float_as_int(v), lane));
}
template <int CTRL>
__device__ __forceinline__ float dpp_add(float x) {
    int y = __builtin_amdgcn_update_dpp(0, __float_as_int(x), CTRL, 0xF, 0xF, true);
    return x + __int_as_float(y);
}
__device__ __forceinline__ float sum16(float x) {
    x = dpp_add<0xB1>(x);    // quad_perm xor1
    x = dpp_add<0x4E>(x);    // quad_perm xor2
    x = dpp_add<0x124>(x);   // row_ror:4
    x = dpp_add<0x128>(x);   // row_ror:8
    return x;
}
__device__ __forceinline__ float swz16(float x) {   // lane ^ 16 within 32-group
    return __int_as_float(__builtin_amdgcn_ds_swizzle(__float_as_int(x), 0x401F));
}

__device__ __forceinline__ const float* w_row(int r, const float* pw, const float* pow_,
                                              const float* pfw, const float* cw) {
    if (r < 8)   return pw   + r * 1536;
    if (r < 16)  return pow_ + (r - 8) * 1536;
    if (r < 144) return pfw  + (r - 16) * 1536;
    return cw + (r - 144) * 1536;
}
__device__ __forceinline__ const float* nw_row(int r, const float* pn, const float* pon,
                                               const float* pfn, const float* cn) {
    if (r < 8)   return pn   + r * 3;
    if (r < 16)  return pon  + (r - 8) * 3;
    if (r < 144) return pfn  + (r - 16) * 3;
    return cn + (r - 144) * 3;
}

// ---------------- kernel B: precompute tables ----------------
__global__ void kB(const float* __restrict__ syms, const float* __restrict__ siv,
                   const float* __restrict__ pw, const float* __restrict__ pn,
                   const float* __restrict__ pow_, const float* __restrict__ pon,
                   const float* __restrict__ pfw, const float* __restrict__ pfn,
                   const float* __restrict__ cw, const float* __restrict__ cn,
                   float* __restrict__ ws) {
    int blk = blockIdx.x, tid = threadIdx.x;
    if (blk < 64) {
        int jj = blk >> 5, e = blk & 31;
        __shared__ float bas[512];
        for (int i = tid; i < 512; i += 256)
            bas[i] = (e == 0) ? 1.0f : ((e == 1) ? siv[i] : syms[(e - 2) * 512 + i]);
        __syncthreads();
        if (tid < NROWS) {
            int c = tid;
            const float4* w4 = (const float4*)(w_row(c, pw, pow_, pfw, cw) + (jj + 1) * 512);
            const float4* b4 = (const float4*)bas;
            float s = 0.f;
            for (int q = 0; q < 128; ++q) {
                float4 a = b4[q], b = w4[q];
                s += a.x * b.x + a.y * b.y + a.z * b.z + a.w * b.w;
            }
            ws[OFF_GI + (jj * 32 + e) * 208 + c] = s;
        }
    } else if (blk == 64) {
        __shared__ float basw[32 * 512];
        for (int i = tid; i < 32 * 512; i += 256) {
            int m = i >> 9, v = i & 511;
            basw[i] = (m == 0) ? 1.0f : ((m == 1) ? siv[v] : syms[(m - 2) * 512 + v]);
        }
        __syncthreads();
        for (int p = tid; p < 1024; p += 256) {
            int m = p >> 5, mm = p & 31;
            const float4* a4 = (const float4*)(basw + m * 512);
            const float4* b4 = (const float4*)(basw + mm * 512);
            float s = 0.f;
            for (int q = 0; q < 128; ++q) {
                float4 a = a4[q], b = b4[q];
                s += a.x * b.x + a.y * b.y + a.z * b.z + a.w * b.w;
            }
            ws[OFF_M + p] = s;
        }
    } else if (blk == 65) {
        for (int idx = tid; idx < 624; idx += 256) {
            int r = idx / 3, j = idx % 3;
            const float4* w4 = (const float4*)(w_row(r, pw, pow_, pfw, cw) + j * 512);
            float s = 0.f;
            for (int q = 0; q < 128; ++q) {
                float4 b = w4[q];
                s += b.x * b.x + b.y * b.y + b.z * b.z + b.w * b.w;
            }
            float nrm = fmaxf(sqrtf(s), 1e-8f);
            float nwv = nw_row(r, pn, pon, pfn, cn)[j];
            float sig = 1.f / (1.f + expf(-nwv));
            ws[OFF_A + idx]  = (2.f * sig - 1.f) / nrm;
            ws[OFF_Bc + idx] = 1.f - sig;
        }
    } else {
        int part = blk - 66;
        _Float16* whp = (_Float16*)(ws + OFF_W0);
        _Float16* wlp = whp + 208 * 512;
        for (int i = tid; i < 6656; i += 256) {
            int flat = part * 6656 + i;
            int c = flat >> 9, v = flat & 511;
            float wv = w_row(c, pw, pow_, pfw, cw)[v];
            _Float16 h = (_Float16)wv;
            whp[flat] = h;
            wlp[flat] = (_Float16)(wv - (float)h);
        }
    }
}

// ---------------- kernel A: interp0 via split-f16 MFMA GEMM (R14) ----------------
__global__ __launch_bounds__(256) void kA(const float* __restrict__ x, float* __restrict__ ws) {
    __shared__ half8 AH[2][256];
    __shared__ half8 AL[2][256];
    __shared__ float red[256];
    __shared__ float invx[64];
    const int tid = threadIdx.x;
    const int wid = tid >> 6, l = tid & 63;
    const int bid = blockIdx.x;
    const size_t bt0 = (size_t)(bid >> 1) * 64;

    const int sr = tid >> 2, ss = tid & 3;
    const float* xp = x + (bt0 + sr) * 512 + ss * 8;
    const int wpos = (sr >> 4) * 64 + (sr & 15) + (ss << 4);

    const _Float16* whp = (const _Float16*)(ws + OFF_W0);
    const _Float16* wlp = whp + 208 * 512;

    const int gw = ((bid & 1) << 2) | wid;
    const int nt = (gw < 5) ? 2 : 1;
    const int t0 = (gw < 5) ? (2 * gw) : (5 + gw);

    f32x4 acc[4][2];
#pragma unroll
    for (int m = 0; m < 4; ++m)
#pragma unroll
        for (int tt = 0; tt < 2; ++tt)
            acc[m][tt] = (f32x4){0.f, 0.f, 0.f, 0.f};

    float sumsq = 0.f;
    {
        float v[8];
        *(float4*)v       = *(const float4*)(xp);
        *(float4*)(v + 4) = *(const float4*)(xp + 4);
        half8 hh, hl;
#pragma unroll
        for (int j = 0; j < 8; ++j) {
            sumsq += v[j] * v[j];
            _Float16 h = (_Float16)v[j];
            hh[j] = h;
            hl[j] = (_Float16)(v[j] - (float)h);
        }
        AH[0][wpos] = hh;
        AL[0][wpos] = hl;
    }
    __syncthreads();

    for (int kt = 0; kt < 16; ++kt) {
        const int buf = kt & 1;
        half8 ahm[4], alm[4];
#pragma unroll
        for (int m = 0; m < 4; ++m) {
            ahm[m] = AH[buf][m * 64 + l];
            alm[m] = AL[buf][m * 64 + l];
        }
        float4 xv0, xv1;
        if (kt < 15) {
            xv0 = *(const float4*)(xp + (kt + 1) * 32);
            xv1 = *(const float4*)(xp + (kt + 1) * 32 + 4);
        }
        const int kof = kt * 32 + (l >> 4) * 8;
#pragma unroll
        for (int tt = 0; tt < 2; ++tt) {
            if (tt < nt) {
                const int c = (t0 + tt) * 16 + (l & 15);
                half8 bh = *(const half8*)(whp + c * 512 + kof);
                half8 bl = *(const half8*)(wlp + c * 512 + kof);
#pragma unroll
                for (int m = 0; m < 4; ++m) {
                    acc[m][tt] = __builtin_amdgcn_mfma_f32_16x16x32_f16(ahm[m], bh, acc[m][tt], 0, 0, 0);
                    acc[m][tt] = __builtin_amdgcn_mfma_f32_16x16x32_f16(ahm[m], bl, acc[m][tt], 0, 0, 0);
                    acc[m][tt] = __builtin_amdgcn_mfma_f32_16x16x32_f16(alm[m], bh, acc[m][tt], 0, 0, 0);
                }
            }
        }
        if (kt < 15) {
            float v[8];
            *(float4*)v = xv0; *(float4*)(v + 4) = xv1;
            half8 hh, hl;
#pragma unroll
            for (int j = 0; j < 8; ++j) {
                sumsq += v[j] * v[j];
                _Float16 h = (_Float16)v[j];
                hh[j] = h;
                hl[j] = (_Float16)(v[j] - (float)h);
            }
            AH[buf ^ 1][wpos] = hh;
            AL[buf ^ 1][wpos] = hl;
        }
        __syncthreads();
    }

    red[tid] = sumsq;
    __syncthreads();
    if (tid < 64) {
        float s = red[tid * 4] + red[tid * 4 + 1] + red[tid * 4 + 2] + red[tid * 4 + 3];
        invx[tid] = 1.f / fmaxf(sqrtf(s), 1e-8f);
    }
    __syncthreads();

#pragma unroll
    for (int tt = 0; tt < 2; ++tt) {
        if (tt < nt) {
            const int c = (t0 + tt) * 16 + (l & 15);
            const float A0 = ws[OFF_A + c * 3];
            const float B0 = ws[OFF_Bc + c * 3];
#pragma unroll
            for (int m = 0; m < 4; ++m) {
                const int rbase = m * 16 + (l >> 4) * 4;
#pragma unroll
                for (int j = 0; j < 4; ++j) {
                    const float ix = invx[rbase + j];
                    ws[OFF_I0 + (bt0 + rbase + j) * 208 + c] = A0 * fabsf(acc[m][tt][j]) * ix + B0;
                }
            }
        }
    }
}

// ---------------- kernel C: R14 scan + tail-phase expansion ----------------
// Scan identical to R14 (kC=121us proven): readlane gather + packed f32x2 FMA,
// 1 barrier/step; wave3 computes oc(t) and stores to LDS ocA[t][36] (pad 36:
// banks (4t+m)%32 distinct -> conflict-free). Tail: expand all 128 steps.
__global__ __attribute__((amdgpu_flat_work_group_size(256, 256), amdgpu_waves_per_eu(1, 1)))
void kC(float* __restrict__ ws, const float* __restrict__ sharp,
        const float* __restrict__ syms, const float* __restrict__ siv,
        float* __restrict__ out) {
    __shared__ float nndL[2][144];
    __shared__ float ocA[SS * 36];
    const int b = blockIdx.x, tid = threadIdx.x;
    const int wid = tid >> 6, l = tid & 63;
    const int k = l >> 5, m = l & 31;
    const int isW3 = (wid == 3);
    const int isRow = (tid < 144);
    const int r = isW3 ? (144 + l) : tid;          // owned NAND row

    const float* GI = ws + OFF_GI;
    // interleaved tables: GM1[i] = {G1[i], M[m][i]}, GM2[i] = {G2[i], M[m][i]}
    f32x2 GM1[32], GM2[32];
#pragma unroll
    for (int i = 0; i < 32; ++i) {
        float mv = ws[OFF_M + m * 32 + i];
        GM1[i] = (f32x2){GI[i * 208 + r], mv};
        GM2[i] = (f32x2){GI[(32 + i) * 208 + r], mv};
    }
    const float A1 = ws[OFF_A + r * 3 + 1],  A2 = ws[OFF_A + r * 3 + 2];
    const float B1 = ws[OFF_Bc + r * 3 + 1], B2 = ws[OFF_Bc + r * 3 + 2];
    const float sh = sharp[k];

    // replicated stack state
    float st[4], p[4];
#pragma unroll
    for (int d = 0; d < 4; ++d) {
        st[d] = (d == 1) ? ((m == 1) ? 1.f : 0.f) : ((m == 0) ? ZOFF : 0.f);
        p[d] = (d == 1) ? 1.f : 0.f;
    }
    float pk = st[0] * p[0] + st[1] * p[1] + st[2] * p[2] + st[3] * p[3];
    float pkOther = __shfl_xor(pk, 32);

    const float* i0base = ws + OFF_I0 + (size_t)b * SS * 208;
    const int ioff = isW3 ? 0 : 1;                 // rows consume i0(t+1), w3 i0(t)
    float i0pro = i0base[r];                       // i0(0) for prologue
    float i0use = i0base[(size_t)ioff * 208 + r];  // rows: i0(1), w3: i0(0)

    // CA: readlane gather; packed f32x2 FMA chains {dot, gram} sharing v0/v1
    auto CA = [&](float pp, float po, float iv) -> float {
        f32x2 a1 = (f32x2){0.f, 0.f}, b1 = (f32x2){0.f, 0.f};
        f32x2 a2 = (f32x2){0.f, 0.f}, b2 = (f32x2){0.f, 0.f};
#pragma unroll
        for (int mm = 0; mm < 32; ++mm) {
            float v0 = rlane(pp, mm);        // pk0[mm]
            float v1 = rlane(pp, 32 + mm);   // pk1[mm]
            if (mm & 1) { b1 += GM1[mm] * v0;  b2 += GM2[mm] * v1; }
            else        { a1 += GM1[mm] * v0;  a2 += GM2[mm] * v1; }
        }
        float dd1 = a1.x + b1.x, gq0 = a1.y + b1.y;
        float dd2 = a2.x + b2.x, gq1 = a2.y + b2.y;
        float pm0 = (k ? po : pp) * gq0;
        float pm1 = (k ? pp : po) * gq1;
        float q0 = sum16(pm0); q0 += swz16(q0);
        float q1 = sum16(pm1); q1 += swz16(q1);
        float iq0 = __frsqrt_rn(fmaxf(q0, 1e-16f));
        float iq1 = __frsqrt_rn(fmaxf(q1, 1e-16f));
        return iv * (A1 * fabsf(dd1) * iq0 + B1) * (A2 * fabsf(dd2) * iq1 + B2);
    };

    // ---- prologue: nnd(0) -> nndL[0] ----
    {
        float nv0 = CA(pk, pkOther, i0pro);
        if (isRow) nndL[0][tid] = nv0;
    }
    __syncthreads();

    for (int t = 0; t < SS; ++t) {
        int nidx = t + 1 + ioff; if (nidx > SS - 1) nidx = SS - 1;
        float i0nxt = i0base[(size_t)nidx * 208 + r];

        const float* nb = nndL[t & 1];
        // ---- gates + push_val + state update (replicated in all waves) ----
        float4 gp4 = *(const float4*)(nb + 4 * k);
        float4 gq4 = *(const float4*)(nb + 8 + 4 * k);
        float prp0 = 1.f / (1.f + __expf((fmaxf(gp4.z, gp4.w) - fmaxf(gp4.x, gp4.y)) * sh));
        float prq0 = 1.f / (1.f + __expf((fmaxf(gq4.z, gq4.w) - fmaxf(gq4.x, gq4.y)) * sh));
        float prp1 = 1.f - prp0, prq1 = 1.f - prq0;
        float prx = 0.f, pry = 0.f;
        if (m >= 2) {
            float2 pr2 = *(const float2*)(nb + 16 + 64 * k + 2 * m - 4);
            prx = pr2.x; pry = pr2.y;
        }
        float4 t30 = *(const float4*)(nb + 16 + 64 * k + 60);
        float pk0m = k ? pkOther : pk;
        float pk1m = k ? pk : pkOther;
        float pvc = prx + pry + (t30.x + t30.y) * pk0m + (t30.z + t30.w) * pk1m;

        float zc = (m == 0) ? ZOFF : 0.f;
        float s1v[4], p1[4];
#pragma unroll
        for (int d = 0; d < 4; ++d) {
            float ps = st[d] * (1.f - p[d]) + zc * p[d];
            s1v[d] = ps * prp0 + st[d] * prp1;
            p1[d] = p[(d + 1) & 3] * prp0 + p[d] * prp1;
        }
#pragma unroll
        for (int d = 0; d < 4; ++d) {
            float pu = p1[(d + 3) & 3];
            float su = s1v[d] * (1.f - pu) + pvc * pu;
            st[d] = su * prq0 + s1v[d] * prq1;
            p[d] = pu * prq0 + p1[d] * prq1;
        }
        float pkp = st[0] * p[0] + st[1] * p[1] + st[2] * p[2] + st[3] * p[3];
        float pkpOth = __shfl_xor(pkp, 32);

        // ---- fused gram + dots + nnd ----
        float nv = CA(pkp, pkpOth, i0use);
        if (isRow) nndL[(t + 1) & 1][tid] = nv;
        if (isW3) {
            // out coords via lane ops over per-lane nnd2 (calc row 144+lane)
            float s60 = rlane(nv, 60), s61 = rlane(nv, 61);
            float s62 = rlane(nv, 62), s63 = rlane(nv, 63);
            int src = (m >= 2) ? (2 * m - 4) : 0;
            float cx = __shfl(nv, src);
            float cy = __shfl(nv, src + 1);
            if (m < 2) { cx = 0.f; cy = 0.f; }
            if (l < 32) {
                float oc = cx + cy + (s60 + s61) * pkp + (s62 + s63) * pkpOth;
                ocA[t * 36 + m] = oc;     // conflict-free (pad 36)
            }
        }
        __syncthreads();   // nndL(t+1) visible for next step
        pk = pkp;
        pkOther = pkpOth;
        i0use = i0nxt;
    }
    __syncthreads();   // ocA complete

    // ---- tail: expand all 128 steps; thread -> 4 cols x 64 steps ----
    {
        const int vc = (tid & 127) * 4;
        const int te0 = (tid >> 7) * 64;
        float4 sv4 = *(const float4*)(siv + vc);
        float4 sy4[30];
#pragma unroll
        for (int mm = 0; mm < 30; ++mm)
            sy4[mm] = *(const float4*)(syms + mm * 512 + vc);
        float* outb = out + (size_t)b * SS * 512 + vc;
        for (int tt = 0; tt < 64; ++tt) {
            const int t = te0 + tt;
            const float* ocp = ocA + t * 36;
            float4 c[8];
#pragma unroll
            for (int q = 0; q < 8; ++q) c[q] = *(const float4*)(ocp + 4 * q);
            const float* cf = &c[0].x;
            float o0 = cf[0] + cf[1] * sv4.x;
            float o1 = cf[0] + cf[1] * sv4.y;
            float o2 = cf[0] + cf[1] * sv4.z;
            float o3 = cf[0] + cf[1] * sv4.w;
#pragma unroll
            for (int mm = 0; mm < 30; ++mm) {
                float cv = cf[2 + mm];
                o0 += cv * sy4[mm].x;
                o1 += cv * sy4[mm].y;
                o2 += cv * sy4[mm].z;
                o3 += cv * sy4[mm].w;
            }
            *(float4*)(outb + (size_t)t * 512) = make_float4(o0, o1, o2, o3);
        }
    }
}

extern "C" void kernel_launch(void* const* d_in, const int* in_sizes, int n_in,
                              void* d_out, int out_size, void* d_ws, size_t ws_size,
                              hipStream_t stream) {
    const float* x    = (const float*)d_in[0];
    const float* syms = (const float*)d_in[1];
    const float* siv  = (const float*)d_in[2];
    const float* shp  = (const float*)d_in[3];
    const float* pw   = (const float*)d_in[4];
    const float* pn   = (const float*)d_in[5];
    const float* pow_ = (const float*)d_in[6];
    const float* pon  = (const float*)d_in[7];
    const float* pfw  = (const float*)d_in[8];
    const float* pfn  = (const float*)d_in[9];
    const float* cw   = (const float*)d_in[10];
    const float* cn   = (const float*)d_in[11];
    float* ws  = (float*)d_ws;
    float* out = (float*)d_out;

    hipLaunchKernelGGL(kB, dim3(82),   dim3(256), 0, stream,
                       syms, siv, pw, pn, pow_, pon, pfw, pfn, cw, cn, ws);
    hipLaunchKernelGGL(kA, dim3(1024), dim3(256), 0, stream, x, ws);
    hipLaunchKernelGGL(kC, dim3(256),  dim3(256), 0, stream, ws, shp, syms, siv, out);
}